// Round 3
// baseline (583.440 us; speedup 1.0000x reference)
//
#include <hip/hip_runtime.h>
#include <math.h>

typedef __attribute__((ext_vector_type(8))) __bf16 bf16x8;
typedef __attribute__((ext_vector_type(8))) short short8;
typedef __attribute__((ext_vector_type(4))) float f32x4;
typedef __attribute__((ext_vector_type(4))) unsigned short u16x4;

#define S_LEN 2048
#define NHEAD 16

__device__ __forceinline__ unsigned short f2b(float f) {
    unsigned int u = __float_as_uint(f);
    u = (u + 0x7fffu + ((u >> 16) & 1u)) >> 16;
    return (unsigned short)u;
}

__device__ __forceinline__ f32x4 mfma16(short8 a, short8 b, f32x4 c) {
    return __builtin_amdgcn_mfma_f32_16x16x32_bf16(
        __builtin_bit_cast(bf16x8, a), __builtin_bit_cast(bf16x8, b), c, 0, 0, 0);
}

#define GLDS(gptr, lptr)                                                              \
    __builtin_amdgcn_global_load_lds(                                                 \
        (const __attribute__((address_space(1))) unsigned int*)(gptr),                \
        (__attribute__((address_space(3))) unsigned int*)(lptr), 16, 0, 0)

// ---------------- fp32 -> bf16 converts ----------------
__global__ __launch_bounds__(256) void cvt_f2b(const float* __restrict__ in,
                                               unsigned short* __restrict__ out, int n4) {
    int i = blockIdx.x * 256 + threadIdx.x;
    if (i >= n4) return;
    float4 v = ((const float4*)in)[i];
    u16x4 o;
    o[0] = f2b(v.x); o[1] = f2b(v.y); o[2] = f2b(v.z); o[3] = f2b(v.w);
    ((u16x4*)out)[i] = o;
}

__global__ __launch_bounds__(256) void cvt_f2b_pad(const float* __restrict__ in,
                                                   unsigned short* __restrict__ out,
                                                   int N, int K, int Npad) {
    int i = blockIdx.x * 256 + threadIdx.x;
    int total4 = Npad * (K >> 2);
    if (i >= total4) return;
    int r = (i * 4) / K;
    u16x4 o = {0, 0, 0, 0};
    if (r < N) {
        float4 v = ((const float4*)in)[i];
        o[0] = f2b(v.x); o[1] = f2b(v.y); o[2] = f2b(v.z); o[3] = f2b(v.w);
    }
    ((u16x4*)out)[i] = o;
}

// ---------------- GEMM: C[M x Npad](f32) = A[M x K](bf16) @ W[Npad x K]^T + bias ----
// m97 pattern: global_load_lds width-16, 128x128 tile, BK=32, 4 waves.
// 1D grid with bijective XCD-chunk swizzle (m204): each XCD gets a contiguous
// range of tiles -> W-panel reuse in its private L2.
__global__ __launch_bounds__(256) void gemm_bt(const unsigned short* __restrict__ A,
                                               const unsigned short* __restrict__ W,
                                               const float* __restrict__ bias,
                                               float* __restrict__ C,
                                               int M, int N, int K, int Npad,
                                               int tiles_m) {
    __shared__ __align__(16) unsigned short sA[128 * 32];
    __shared__ __align__(16) unsigned short sB[128 * 32];
    const int tid = threadIdx.x;
    const int wave = tid >> 6, lane = tid & 63;
    const int l15 = lane & 15, l4 = lane >> 4;
    const int wm = wave >> 1, wn = wave & 1;

    const int nwg = gridDim.x;
    const int q8 = nwg >> 3, r8 = nwg & 7;
    const int xcd = blockIdx.x & 7, ii = blockIdx.x >> 3;
    const int sw = ((xcd < r8) ? xcd * (q8 + 1) : r8 * (q8 + 1) + (xcd - r8) * q8) + ii;
    const int bm = sw % tiles_m, bn = sw / tiles_m;

    f32x4 acc[4][4] = {};
    const int nkt = K >> 5;
    for (int kt = 0; kt < nkt; ++kt) {
#pragma unroll
        for (int j = 0; j < 2; ++j) {
            int cbase = (j * 4 + wave) * 64;
            int c = cbase + lane;
            int r = c >> 2, c8 = c & 3;
            GLDS(&A[(size_t)(bm * 128 + r) * K + kt * 32 + c8 * 8],
                 (char*)sA + cbase * 16);
            GLDS(&W[(size_t)(bn * 128 + r) * K + kt * 32 + c8 * 8],
                 (char*)sB + cbase * 16);
        }
        __syncthreads();
        short8 af[4], bf[4];
#pragma unroll
        for (int mi = 0; mi < 4; ++mi)
            af[mi] = *(const short8*)&sA[(wm * 64 + mi * 16 + l15) * 32 + 8 * l4];
#pragma unroll
        for (int ni = 0; ni < 4; ++ni)
            bf[ni] = *(const short8*)&sB[(wn * 64 + ni * 16 + l15) * 32 + 8 * l4];
#pragma unroll
        for (int mi = 0; mi < 4; ++mi)
#pragma unroll
            for (int ni = 0; ni < 4; ++ni)
                acc[mi][ni] = mfma16(af[mi], bf[ni], acc[mi][ni]);
        __syncthreads();
    }
#pragma unroll
    for (int mi = 0; mi < 4; ++mi) {
        int row = bm * 128 + wm * 64 + mi * 16 + 4 * l4;
#pragma unroll
        for (int ni = 0; ni < 4; ++ni) {
            int col = bn * 128 + wn * 64 + ni * 16 + l15;
            float b = (col < N) ? bias[col] : 0.f;
#pragma unroll
            for (int r = 0; r < 4; ++r)
                C[(size_t)(row + r) * Npad + col] = acc[mi][ni][r] + b;
        }
    }
}

// ---------------- RMS norm ----------------
__global__ __launch_bounds__(256) void rmsnorm_k(const float* __restrict__ in,
                                                 const float* __restrict__ w,
                                                 unsigned short* __restrict__ out,
                                                 int K, int ldin) {
    int row = blockIdx.x, tid = threadIdx.x;
    const float* p = in + (size_t)row * ldin;
    float ss = 0.f;
    for (int i = tid; i < K; i += 256) { float v = p[i]; ss += v * v; }
#pragma unroll
    for (int off = 1; off < 64; off <<= 1) ss += __shfl_xor(ss, off, 64);
    __shared__ float red[4];
    if ((tid & 63) == 0) red[tid >> 6] = ss;
    __syncthreads();
    float tot = red[0] + red[1] + red[2] + red[3];
    float rinv = rsqrtf(tot / (float)K + 1e-6f);
    for (int i = tid; i < K; i += 256)
        out[(size_t)row * K + i] = f2b(p[i] * rinv * w[i]);
}

// ---------------- assemble q ----------------
__global__ __launch_bounds__(256) void assemble_q(const float* __restrict__ qup,
                                                  const float* __restrict__ fcos,
                                                  const float* __restrict__ fsin,
                                                  unsigned short* __restrict__ qf) {
    int s = blockIdx.x, tid = threadIdx.x;
    const float scale = 0.07216878365f;  // 192^-0.5
    for (int idx = tid; idx < NHEAD * 128; idx += 256) {
        int h = idx >> 7, j = idx & 127;
        qf[((size_t)h * S_LEN + s) * 192 + j] = f2b(qup[(size_t)s * 3072 + h * 192 + j] * scale);
    }
    for (int idx = tid; idx < NHEAD * 32; idx += 256) {
        int h = idx >> 5, j = idx & 31;
        float x0 = qup[(size_t)s * 3072 + h * 192 + 128 + 2 * j];
        float x1 = qup[(size_t)s * 3072 + h * 192 + 128 + 2 * j + 1];
        float c = fcos[s * 32 + j], sn = fsin[s * 32 + j];
        size_t base = ((size_t)h * S_LEN + s) * 192 + 128 + 2 * j;
        qf[base]     = f2b((x0 * c - x1 * sn) * scale);
        qf[base + 1] = f2b((x0 * sn + x1 * c) * scale);
    }
}

// ---------------- assemble k ----------------
__global__ __launch_bounds__(256) void assemble_k(const float* __restrict__ kvup,
                                                  const float* __restrict__ kvd,
                                                  const float* __restrict__ fcos,
                                                  const float* __restrict__ fsin,
                                                  unsigned short* __restrict__ kf) {
    int s = blockIdx.x, tid = threadIdx.x;
    __shared__ unsigned short pe[64];
    if (tid < 32) {
        int j = tid;
        float x0 = kvd[(size_t)s * 640 + 512 + 2 * j];
        float x1 = kvd[(size_t)s * 640 + 512 + 2 * j + 1];
        float c = fcos[s * 32 + j], sn = fsin[s * 32 + j];
        pe[2 * j]     = f2b(x0 * c - x1 * sn);
        pe[2 * j + 1] = f2b(x0 * sn + x1 * c);
    }
    __syncthreads();
    for (int idx = tid; idx < NHEAD * 128; idx += 256) {
        int h = idx >> 7, j = idx & 127;
        kf[((size_t)h * S_LEN + s) * 192 + j] = f2b(kvup[(size_t)s * 4096 + h * 256 + j]);
    }
    for (int idx = tid; idx < NHEAD * 64; idx += 256) {
        int h = idx >> 6, j = idx & 63;
        kf[((size_t)h * S_LEN + s) * 192 + 128 + j] = pe[j];
    }
}

// ---------------- assemble v: tiled transpose, coalesced short8 stores ----------
__global__ __launch_bounds__(256) void assemble_v(const float* __restrict__ kvup,
                                                  unsigned short* __restrict__ vT) {
    __shared__ unsigned short t[64][136];
    int sb = blockIdx.x, h = blockIdx.y, tid = threadIdx.x;
#pragma unroll
    for (int i = 0; i < 8; ++i) {
        int idx = tid + i * 256;
        int s = idx >> 5, c4 = idx & 31;
        float4 v = *(const float4*)&kvup[(size_t)(sb * 64 + s) * 4096 + h * 256 + 128 + c4 * 4];
        t[s][c4 * 4 + 0] = f2b(v.x); t[s][c4 * 4 + 1] = f2b(v.y);
        t[s][c4 * 4 + 2] = f2b(v.z); t[s][c4 * 4 + 3] = f2b(v.w);
    }
    __syncthreads();
#pragma unroll
    for (int i = 0; i < 4; ++i) {
        int idx = tid + i * 256;
        int d = idx >> 3, s8 = idx & 7;
        short8 o;
#pragma unroll
        for (int j = 0; j < 8; ++j) o[j] = t[s8 * 8 + j][d];
        *(short8*)&vT[((size_t)h * 128 + d) * S_LEN + sb * 64 + s8 * 8] = o;
    }
}

// ---------------- flash attention, causal ----------------
// grid 512 flat: h = bid&15, qb balanced so pairs sum to 33 iters.
// XOR-swizzled LDS; register double-buffer for K/V; launch_bounds(256,2) so the
// prefetch regs LIVE IN REGISTERS (round-2's default cap of 108 spilled them to
// scratch: 172 MB of HBM writes per dispatch).
__global__ __launch_bounds__(256, 2) void flash_attn(const unsigned short* __restrict__ qf,
                                                     const unsigned short* __restrict__ kf,
                                                     const unsigned short* __restrict__ vT,
                                                     unsigned short* __restrict__ attn) {
    __shared__ __align__(16) unsigned short sK[64 * 192];   // logical [64][192], swizzled
    __shared__ __align__(16) unsigned short sV[128 * 64];   // logical [128][64], swizzled
    __shared__ __align__(16) unsigned short sP[4 * 16 * 64];// logical [4][16][64], swizzled
    const int tid = threadIdx.x;
    const int wave = tid >> 6, lane = tid & 63;
    const int l15 = lane & 15, l4 = lane >> 4;
    const int bid = blockIdx.x;
    const int h = bid & 15, iph = bid >> 4;
    const int qb = (iph < 16) ? iph : 47 - iph;

    const unsigned short* kbase = kf + (size_t)h * S_LEN * 192;
    const unsigned short* vbase = vT + (size_t)h * 128 * S_LEN;

    short8 qfrag[6];
    {
        const unsigned short* qp =
            qf + ((size_t)h * S_LEN + qb * 64 + wave * 16 + l15) * 192 + 8 * l4;
#pragma unroll
        for (int ks = 0; ks < 6; ++ks) qfrag[ks] = *(const short8*)(qp + ks * 32);
    }
    f32x4 oacc[8] = {};
    float m_r[4] = {-INFINITY, -INFINITY, -INFINITY, -INFINITY};
    float l_r[4] = {0.f, 0.f, 0.f, 0.f};

    uint4 kreg[6], vreg[4];
#pragma unroll
    for (int i = 0; i < 6; ++i) {
        int c = tid + i * 256, r = c / 24, c8 = c % 24;
        kreg[i] = *(const uint4*)&kbase[(size_t)r * 192 + c8 * 8];
    }
#pragma unroll
    for (int i = 0; i < 4; ++i) {
        int c = tid + i * 256, d = c >> 3, k8 = c & 7;
        vreg[i] = *(const uint4*)&vbase[(size_t)d * S_LEN + k8 * 8];
    }

    for (int kb = 0; kb <= qb; ++kb) {
#pragma unroll
        for (int i = 0; i < 6; ++i) {
            int c = tid + i * 256, r = c / 24, c8 = c % 24;
            *(uint4*)((char*)sK + r * 384 + ((c8 ^ (r & 7)) * 16)) = kreg[i];
        }
#pragma unroll
        for (int i = 0; i < 4; ++i) {
            int c = tid + i * 256, d = c >> 3, k8 = c & 7;
            *(uint4*)((char*)sV + d * 128 + ((k8 ^ (d & 7)) * 16)) = vreg[i];
        }
        __syncthreads();
        if (kb < qb) {
#pragma unroll
            for (int i = 0; i < 6; ++i) {
                int c = tid + i * 256, r = c / 24, c8 = c % 24;
                kreg[i] = *(const uint4*)&kbase[(size_t)((kb + 1) * 64 + r) * 192 + c8 * 8];
            }
#pragma unroll
            for (int i = 0; i < 4; ++i) {
                int c = tid + i * 256, d = c >> 3, k8 = c & 7;
                vreg[i] = *(const uint4*)&vbase[(size_t)d * S_LEN + (kb + 1) * 64 + k8 * 8];
            }
        }

        f32x4 sc[4] = {};
#pragma unroll
        for (int ks = 0; ks < 6; ++ks)
#pragma unroll
            for (int ni = 0; ni < 4; ++ni) {
                int r = ni * 16 + l15;
                short8 bfr = *(const short8*)((char*)sK + r * 384 + (((ks * 4 + l4) ^ (r & 7)) * 16));
                sc[ni] = mfma16(qfrag[ks], bfr, sc[ni]);
            }

        const bool diag = (kb == qb);
        float p[4][4], alpha[4];
#pragma unroll
        for (int r = 0; r < 4; ++r) {
            int qrow = wave * 16 + 4 * l4 + r;
            float mx = -1e30f;
#pragma unroll
            for (int ni = 0; ni < 4; ++ni) {
                float sv = sc[ni][r];
                if (diag && (ni * 16 + l15 > qrow)) sv = -1e30f;
                p[ni][r] = sv;
                mx = fmaxf(mx, sv);
            }
#pragma unroll
            for (int off = 1; off < 16; off <<= 1) mx = fmaxf(mx, __shfl_xor(mx, off, 16));
            float mnew = fmaxf(m_r[r], mx);
            alpha[r] = __expf(m_r[r] - mnew);
            float rs = 0.f;
#pragma unroll
            for (int ni = 0; ni < 4; ++ni) {
                float pe = __expf(p[ni][r] - mnew);
                p[ni][r] = pe;
                rs += pe;
            }
#pragma unroll
            for (int off = 1; off < 16; off <<= 1) rs += __shfl_xor(rs, off, 16);
            l_r[r] = l_r[r] * alpha[r] + rs;
            m_r[r] = mnew;
        }
#pragma unroll
        for (int ni2 = 0; ni2 < 8; ++ni2)
#pragma unroll
            for (int r = 0; r < 4; ++r) oacc[ni2][r] *= alpha[r];
#pragma unroll
        for (int ni = 0; ni < 4; ++ni)
#pragma unroll
            for (int r = 0; r < 4; ++r) {
                int prow = 4 * l4 + r;
                int pbyte = wave * 2048 + ((prow * 128 + (ni * 16 + l15) * 2) ^ ((prow & 7) << 4));
                *(unsigned short*)((char*)sP + pbyte) = f2b(p[ni][r]);
            }
#pragma unroll
        for (int ks2 = 0; ks2 < 2; ++ks2) {
            short8 pa = *(const short8*)((char*)sP + wave * 2048 + l15 * 128 +
                                         (((ks2 * 4 + l4) ^ (l15 & 7)) * 16));
#pragma unroll
            for (int ni2 = 0; ni2 < 8; ++ni2) {
                int d = ni2 * 16 + l15;
                short8 vb = *(const short8*)((char*)sV + d * 128 +
                                             (((ks2 * 4 + l4) ^ (d & 7)) * 16));
                oacc[ni2] = mfma16(pa, vb, oacc[ni2]);
            }
        }
        __syncthreads();
    }
#pragma unroll
    for (int ni2 = 0; ni2 < 8; ++ni2) {
        int col = h * 128 + ni2 * 16 + l15;
#pragma unroll
        for (int r = 0; r < 4; ++r) {
            int row = qb * 64 + wave * 16 + 4 * l4 + r;
            attn[(size_t)row * 2048 + col] = f2b(oacc[ni2][r] / l_r[r]);
        }
    }
}

extern "C" void kernel_launch(void* const* d_in, const int* in_sizes, int n_in,
                              void* d_out, int out_size, void* d_ws, size_t ws_size,
                              hipStream_t stream) {
    (void)in_sizes; (void)n_in; (void)out_size; (void)ws_size;
    const float* x    = (const float*)d_in[0];
    const float* fcos = (const float*)d_in[2];
    const float* fsin = (const float*)d_in[3];
    const float* wqd  = (const float*)d_in[5];
    const float* bqd  = (const float*)d_in[6];
    const float* qnw  = (const float*)d_in[7];
    const float* wqu  = (const float*)d_in[8];
    const float* bqu  = (const float*)d_in[9];
    const float* wkvd = (const float*)d_in[10];
    const float* bkvd = (const float*)d_in[11];
    const float* kvnw = (const float*)d_in[12];
    const float* wkvu = (const float*)d_in[13];
    const float* bkvu = (const float*)d_in[14];
    const float* wo   = (const float*)d_in[15];
    const float* bwo  = (const float*)d_in[16];
    float* out = (float*)d_out;

    char* ws = (char*)d_ws;
    size_t off = 0;
    auto alloc = [&](size_t bytes) {
        void* p = ws + off;
        off += (bytes + 255) & ~(size_t)255;
        return p;
    };
    unsigned short* xb     = (unsigned short*)alloc(2048ull * 2048 * 2);
    unsigned short* wqd16  = (unsigned short*)alloc(1536ull * 2048 * 2);
    unsigned short* wqu16  = (unsigned short*)alloc(3072ull * 1536 * 2);
    unsigned short* wkvd16 = (unsigned short*)alloc(640ull * 2048 * 2);
    unsigned short* wkvu16 = (unsigned short*)alloc(4096ull * 512 * 2);
    char* slotA            = (char*)alloc(2048ull * 3072 * 4);  // qdown f32 | qup f32 | attn bf16
    unsigned short* qn16   = (unsigned short*)alloc(2048ull * 1536 * 2);
    unsigned short* qf16   = (unsigned short*)alloc(16ull * 2048 * 192 * 2);
    float* kvd32           = (float*)alloc(2048ull * 640 * 4);
    unsigned short* kvn16  = (unsigned short*)alloc(2048ull * 512 * 2);
    char* slotB            = (char*)alloc(2048ull * 4096 * 4);  // kvup f32 | wo bf16
    unsigned short* kf16   = (unsigned short*)alloc(16ull * 2048 * 192 * 2);
    unsigned short* vT16   = (unsigned short*)alloc(16ull * 128 * 2048 * 2);

    float* qdown32 = (float*)slotA;
    float* qup32   = (float*)slotA;
    unsigned short* attn16 = (unsigned short*)slotA;
    float* kvup32  = (float*)slotB;
    unsigned short* wo16 = (unsigned short*)slotB;

    // weight / activation converts
    cvt_f2b<<<4096, 256, 0, stream>>>(x, xb, 2048 * 2048 / 4);
    cvt_f2b<<<3072, 256, 0, stream>>>(wqd, wqd16, 1536 * 2048 / 4);
    cvt_f2b<<<4608, 256, 0, stream>>>(wqu, wqu16, 3072 * 1536 / 4);
    cvt_f2b_pad<<<1280, 256, 0, stream>>>(wkvd, wkvd16, 576, 2048, 640);
    cvt_f2b<<<2048, 256, 0, stream>>>(wkvu, wkvu16, 4096 * 512 / 4);

    // q path
    gemm_bt<<<16 * 12, 256, 0, stream>>>(xb, wqd16, bqd, qdown32, 2048, 1536, 2048, 1536, 16);
    rmsnorm_k<<<2048, 256, 0, stream>>>(qdown32, qnw, qn16, 1536, 1536);
    gemm_bt<<<16 * 24, 256, 0, stream>>>(qn16, wqu16, bqu, qup32, 2048, 3072, 1536, 3072, 16);

    // kv path
    gemm_bt<<<16 * 5, 256, 0, stream>>>(xb, wkvd16, bkvd, kvd32, 2048, 576, 2048, 640, 16);
    rmsnorm_k<<<2048, 256, 0, stream>>>(kvd32, kvnw, kvn16, 512, 640);
    gemm_bt<<<16 * 32, 256, 0, stream>>>(kvn16, wkvu16, bkvu, kvup32, 2048, 4096, 512, 4096, 16);

    // assemble attention operands
    assemble_q<<<2048, 256, 0, stream>>>(qup32, fcos, fsin, qf16);
    assemble_k<<<2048, 256, 0, stream>>>(kvup32, kvd32, fcos, fsin, kf16);
    assemble_v<<<dim3(32, 16), 256, 0, stream>>>(kvup32, vT16);

    // wo weights into slotB (kvup dead after assembles)
    cvt_f2b<<<4096, 256, 0, stream>>>(wo, wo16, 2048 * 2048 / 4);

    // attention + output projection
    flash_attn<<<512, 256, 0, stream>>>(qf16, kf16, vT16, attn16);
    gemm_bt<<<16 * 16, 256, 0, stream>>>(attn16, wo16, bwo, out, 2048, 2048, 2048, 2048, 16);
}

// Round 6
// 489.783 us; speedup vs baseline: 1.1912x; 1.1912x over previous
//
#include <hip/hip_runtime.h>
#include <math.h>

typedef __attribute__((ext_vector_type(8))) __bf16 bf16x8;
typedef __attribute__((ext_vector_type(8))) short short8;
typedef __attribute__((ext_vector_type(4))) float f32x4;
typedef __attribute__((ext_vector_type(4))) unsigned short u16x4;

#define S_LEN 2048
#define NHEAD 16

__device__ __forceinline__ unsigned short f2b(float f) {
    unsigned int u = __float_as_uint(f);
    u = (u + 0x7fffu + ((u >> 16) & 1u)) >> 16;
    return (unsigned short)u;
}

__device__ __forceinline__ f32x4 mfma16(short8 a, short8 b, f32x4 c) {
    return __builtin_amdgcn_mfma_f32_16x16x32_bf16(
        __builtin_bit_cast(bf16x8, a), __builtin_bit_cast(bf16x8, b), c, 0, 0, 0);
}

#define GLDS(gptr, lptr)                                                              \
    __builtin_amdgcn_global_load_lds(                                                 \
        (const __attribute__((address_space(1))) unsigned int*)(gptr),                \
        (__attribute__((address_space(3))) unsigned int*)(lptr), 16, 0, 0)

// ---------------- fp32 -> bf16 converts ----------------
__global__ __launch_bounds__(256) void cvt_f2b(const float* __restrict__ in,
                                               unsigned short* __restrict__ out, int n4) {
    int i = blockIdx.x * 256 + threadIdx.x;
    if (i >= n4) return;
    float4 v = ((const float4*)in)[i];
    u16x4 o;
    o[0] = f2b(v.x); o[1] = f2b(v.y); o[2] = f2b(v.z); o[3] = f2b(v.w);
    ((u16x4*)out)[i] = o;
}

__global__ __launch_bounds__(256) void cvt_f2b_pad(const float* __restrict__ in,
                                                   unsigned short* __restrict__ out,
                                                   int N, int K, int Npad) {
    int i = blockIdx.x * 256 + threadIdx.x;
    int total4 = Npad * (K >> 2);
    if (i >= total4) return;
    int r = (i * 4) / K;
    u16x4 o = {0, 0, 0, 0};
    if (r < N) {
        float4 v = ((const float4*)in)[i];
        o[0] = f2b(v.x); o[1] = f2b(v.y); o[2] = f2b(v.z); o[3] = f2b(v.w);
    }
    ((u16x4*)out)[i] = o;
}

// ---------------- GEMM: C[M x Npad](f32) = A[M x K](bf16) @ W[Npad x K]^T + bias ----
__global__ __launch_bounds__(256) void gemm_bt(const unsigned short* __restrict__ A,
                                               const unsigned short* __restrict__ W,
                                               const float* __restrict__ bias,
                                               float* __restrict__ C,
                                               int M, int N, int K, int Npad,
                                               int tiles_m) {
    __shared__ __align__(16) unsigned short sA[128 * 32];
    __shared__ __align__(16) unsigned short sB[128 * 32];
    const int tid = threadIdx.x;
    const int wave = tid >> 6, lane = tid & 63;
    const int l15 = lane & 15, l4 = lane >> 4;
    const int wm = wave >> 1, wn = wave & 1;

    const int nwg = gridDim.x;
    const int q8 = nwg >> 3, r8 = nwg & 7;
    const int xcd = blockIdx.x & 7, ii = blockIdx.x >> 3;
    const int sw = ((xcd < r8) ? xcd * (q8 + 1) : r8 * (q8 + 1) + (xcd - r8) * q8) + ii;
    const int bm = sw % tiles_m, bn = sw / tiles_m;

    f32x4 acc[4][4] = {};
    const int nkt = K >> 5;
    for (int kt = 0; kt < nkt; ++kt) {
#pragma unroll
        for (int j = 0; j < 2; ++j) {
            int cbase = (j * 4 + wave) * 64;
            int c = cbase + lane;
            int r = c >> 2, c8 = c & 3;
            GLDS(&A[(size_t)(bm * 128 + r) * K + kt * 32 + c8 * 8],
                 (char*)sA + cbase * 16);
            GLDS(&W[(size_t)(bn * 128 + r) * K + kt * 32 + c8 * 8],
                 (char*)sB + cbase * 16);
        }
        __syncthreads();
        short8 af[4], bf[4];
#pragma unroll
        for (int mi = 0; mi < 4; ++mi)
            af[mi] = *(const short8*)&sA[(wm * 64 + mi * 16 + l15) * 32 + 8 * l4];
#pragma unroll
        for (int ni = 0; ni < 4; ++ni)
            bf[ni] = *(const short8*)&sB[(wn * 64 + ni * 16 + l15) * 32 + 8 * l4];
#pragma unroll
        for (int mi = 0; mi < 4; ++mi)
#pragma unroll
            for (int ni = 0; ni < 4; ++ni)
                acc[mi][ni] = mfma16(af[mi], bf[ni], acc[mi][ni]);
        __syncthreads();
    }
#pragma unroll
    for (int mi = 0; mi < 4; ++mi) {
        int row = bm * 128 + wm * 64 + mi * 16 + 4 * l4;
#pragma unroll
        for (int ni = 0; ni < 4; ++ni) {
            int col = bn * 128 + wn * 64 + ni * 16 + l15;
            float b = (col < N) ? bias[col] : 0.f;
#pragma unroll
            for (int r = 0; r < 4; ++r)
                C[(size_t)(row + r) * Npad + col] = acc[mi][ni][r] + b;
        }
    }
}

// ---------------- RMS norm ----------------
__global__ __launch_bounds__(256) void rmsnorm_k(const float* __restrict__ in,
                                                 const float* __restrict__ w,
                                                 unsigned short* __restrict__ out,
                                                 int K, int ldin) {
    int row = blockIdx.x, tid = threadIdx.x;
    const float* p = in + (size_t)row * ldin;
    float ss = 0.f;
    for (int i = tid; i < K; i += 256) { float v = p[i]; ss += v * v; }
#pragma unroll
    for (int off = 1; off < 64; off <<= 1) ss += __shfl_xor(ss, off, 64);
    __shared__ float red[4];
    if ((tid & 63) == 0) red[tid >> 6] = ss;
    __syncthreads();
    float tot = red[0] + red[1] + red[2] + red[3];
    float rinv = rsqrtf(tot / (float)K + 1e-6f);
    for (int i = tid; i < K; i += 256)
        out[(size_t)row * K + i] = f2b(p[i] * rinv * w[i]);
}

// ---------------- assemble q ----------------
__global__ __launch_bounds__(256) void assemble_q(const float* __restrict__ qup,
                                                  const float* __restrict__ fcos,
                                                  const float* __restrict__ fsin,
                                                  unsigned short* __restrict__ qf) {
    int s = blockIdx.x, tid = threadIdx.x;
    const float scale = 0.07216878365f;  // 192^-0.5
    for (int idx = tid; idx < NHEAD * 128; idx += 256) {
        int h = idx >> 7, j = idx & 127;
        qf[((size_t)h * S_LEN + s) * 192 + j] = f2b(qup[(size_t)s * 3072 + h * 192 + j] * scale);
    }
    for (int idx = tid; idx < NHEAD * 32; idx += 256) {
        int h = idx >> 5, j = idx & 31;
        float x0 = qup[(size_t)s * 3072 + h * 192 + 128 + 2 * j];
        float x1 = qup[(size_t)s * 3072 + h * 192 + 128 + 2 * j + 1];
        float c = fcos[s * 32 + j], sn = fsin[s * 32 + j];
        size_t base = ((size_t)h * S_LEN + s) * 192 + 128 + 2 * j;
        qf[base]     = f2b((x0 * c - x1 * sn) * scale);
        qf[base + 1] = f2b((x0 * sn + x1 * c) * scale);
    }
}

// ---------------- assemble k ----------------
__global__ __launch_bounds__(256) void assemble_k(const float* __restrict__ kvup,
                                                  const float* __restrict__ kvd,
                                                  const float* __restrict__ fcos,
                                                  const float* __restrict__ fsin,
                                                  unsigned short* __restrict__ kf) {
    int s = blockIdx.x, tid = threadIdx.x;
    __shared__ unsigned short pe[64];
    if (tid < 32) {
        int j = tid;
        float x0 = kvd[(size_t)s * 640 + 512 + 2 * j];
        float x1 = kvd[(size_t)s * 640 + 512 + 2 * j + 1];
        float c = fcos[s * 32 + j], sn = fsin[s * 32 + j];
        pe[2 * j]     = f2b(x0 * c - x1 * sn);
        pe[2 * j + 1] = f2b(x0 * sn + x1 * c);
    }
    __syncthreads();
    for (int idx = tid; idx < NHEAD * 128; idx += 256) {
        int h = idx >> 7, j = idx & 127;
        kf[((size_t)h * S_LEN + s) * 192 + j] = f2b(kvup[(size_t)s * 4096 + h * 256 + j]);
    }
    for (int idx = tid; idx < NHEAD * 64; idx += 256) {
        int h = idx >> 6, j = idx & 63;
        kf[((size_t)h * S_LEN + s) * 192 + 128 + j] = pe[j];
    }
}

// ---------------- assemble v: tiled transpose, coalesced short8 stores ----------
__global__ __launch_bounds__(256) void assemble_v(const float* __restrict__ kvup,
                                                  unsigned short* __restrict__ vT) {
    __shared__ unsigned short t[64][136];
    int sb = blockIdx.x, h = blockIdx.y, tid = threadIdx.x;
#pragma unroll
    for (int i = 0; i < 8; ++i) {
        int idx = tid + i * 256;
        int s = idx >> 5, c4 = idx & 31;
        float4 v = *(const float4*)&kvup[(size_t)(sb * 64 + s) * 4096 + h * 256 + 128 + c4 * 4];
        t[s][c4 * 4 + 0] = f2b(v.x); t[s][c4 * 4 + 1] = f2b(v.y);
        t[s][c4 * 4 + 2] = f2b(v.z); t[s][c4 * 4 + 3] = f2b(v.w);
    }
    __syncthreads();
#pragma unroll
    for (int i = 0; i < 4; ++i) {
        int idx = tid + i * 256;
        int d = idx >> 3, s8 = idx & 7;
        short8 o;
#pragma unroll
        for (int j = 0; j < 8; ++j) o[j] = t[s8 * 8 + j][d];
        *(short8*)&vT[((size_t)h * 128 + d) * S_LEN + sb * 64 + s8 * 8] = o;
    }
}

// ---------------- flash attention, causal ----------------
// grid 512 flat, balanced qb pairing. Staging via global_load_lds width-16:
// linear LDS dest + PRE-SWIZZLED per-lane global source (same XOR involution as
// the read side), so LDS holds the swizzled layout with zero bank conflicts and
// no register round-trip (round-2/3's reg prefetch spilled to scratch: 150+ MB
// of HBM writes per dispatch).
__global__ __launch_bounds__(256) void flash_attn(const unsigned short* __restrict__ qf,
                                                  const unsigned short* __restrict__ kf,
                                                  const unsigned short* __restrict__ vT,
                                                  unsigned short* __restrict__ attn) {
    __shared__ __align__(16) unsigned short sK[64 * 192];    // logical [64][192], swizzled
    __shared__ __align__(16) unsigned short sV[128 * 64];    // logical [128][64], swizzled
    __shared__ __align__(16) unsigned short sP[4 * 16 * 64]; // logical [4][16][64], swizzled
    const int tid = threadIdx.x;
    const int wave = tid >> 6, lane = tid & 63;
    const int l15 = lane & 15, l4 = lane >> 4;
    const int bid = blockIdx.x;
    const int h = bid & 15, iph = bid >> 4;
    const int qb = (iph < 16) ? iph : 47 - iph;

    const unsigned short* kbase = kf + (size_t)h * S_LEN * 192;
    const unsigned short* vbase = vT + (size_t)h * 128 * S_LEN;

    // per-lane pre-swizzled source offsets (loop-invariant): LDS linear chunk
    // c = i*256+tid must receive logical chunk (r, c8 ^ (r&7)).
    int ksrc[6];
#pragma unroll
    for (int i = 0; i < 6; ++i) {
        int c = i * 256 + tid, r = c / 24, c8 = c % 24;
        ksrc[i] = r * 192 + (c8 ^ (r & 7)) * 8;
    }
    int vsrc[4];
#pragma unroll
    for (int i = 0; i < 4; ++i) {
        int c = i * 256 + tid, d = c >> 3, k8 = c & 7;
        vsrc[i] = d * S_LEN + (k8 ^ (d & 7)) * 8;
    }

    short8 qfrag[6];
    {
        const unsigned short* qp =
            qf + ((size_t)h * S_LEN + qb * 64 + wave * 16 + l15) * 192 + 8 * l4;
#pragma unroll
        for (int ks = 0; ks < 6; ++ks) qfrag[ks] = *(const short8*)(qp + ks * 32);
    }
    f32x4 oacc[8] = {};
    float m_r[4] = {-INFINITY, -INFINITY, -INFINITY, -INFINITY};
    float l_r[4] = {0.f, 0.f, 0.f, 0.f};

    for (int kb = 0; kb <= qb; ++kb) {
        const unsigned short* kt = kbase + (size_t)kb * 64 * 192;
        const unsigned short* vt = vbase + (size_t)kb * 64;
#pragma unroll
        for (int i = 0; i < 6; ++i)
            GLDS(kt + ksrc[i], (char*)sK + (i * 256 + wave * 64) * 16);
#pragma unroll
        for (int i = 0; i < 4; ++i)
            GLDS(vt + vsrc[i], (char*)sV + (i * 256 + wave * 64) * 16);
        __syncthreads();

        f32x4 sc[4] = {};
#pragma unroll
        for (int ks = 0; ks < 6; ++ks)
#pragma unroll
            for (int ni = 0; ni < 4; ++ni) {
                int r = ni * 16 + l15;
                short8 bfr = *(const short8*)((char*)sK + r * 384 + (((ks * 4 + l4) ^ (r & 7)) * 16));
                sc[ni] = mfma16(qfrag[ks], bfr, sc[ni]);
            }

        const bool diag = (kb == qb);
        float p[4][4], alpha[4];
#pragma unroll
        for (int r = 0; r < 4; ++r) {
            int qrow = wave * 16 + 4 * l4 + r;
            float mx = -1e30f;
#pragma unroll
            for (int ni = 0; ni < 4; ++ni) {
                float sv = sc[ni][r];
                if (diag && (ni * 16 + l15 > qrow)) sv = -1e30f;
                p[ni][r] = sv;
                mx = fmaxf(mx, sv);
            }
#pragma unroll
            for (int off = 1; off < 16; off <<= 1) mx = fmaxf(mx, __shfl_xor(mx, off, 16));
            float mnew = fmaxf(m_r[r], mx);
            alpha[r] = __expf(m_r[r] - mnew);
            float rs = 0.f;
#pragma unroll
            for (int ni = 0; ni < 4; ++ni) {
                float pe = __expf(p[ni][r] - mnew);
                p[ni][r] = pe;
                rs += pe;
            }
#pragma unroll
            for (int off = 1; off < 16; off <<= 1) rs += __shfl_xor(rs, off, 16);
            l_r[r] = l_r[r] * alpha[r] + rs;
            m_r[r] = mnew;
        }
#pragma unroll
        for (int ni2 = 0; ni2 < 8; ++ni2)
#pragma unroll
            for (int r = 0; r < 4; ++r) oacc[ni2][r] *= alpha[r];
#pragma unroll
        for (int ni = 0; ni < 4; ++ni)
#pragma unroll
            for (int r = 0; r < 4; ++r) {
                int prow = 4 * l4 + r;
                int pbyte = wave * 2048 + ((prow * 128 + (ni * 16 + l15) * 2) ^ ((prow & 7) << 4));
                *(unsigned short*)((char*)sP + pbyte) = f2b(p[ni][r]);
            }
#pragma unroll
        for (int ks2 = 0; ks2 < 2; ++ks2) {
            short8 pa = *(const short8*)((char*)sP + wave * 2048 + l15 * 128 +
                                         (((ks2 * 4 + l4) ^ (l15 & 7)) * 16));
#pragma unroll
            for (int ni2 = 0; ni2 < 8; ++ni2) {
                int d = ni2 * 16 + l15;
                short8 vb = *(const short8*)((char*)sV + d * 128 +
                                             (((ks2 * 4 + l4) ^ (d & 7)) * 16));
                oacc[ni2] = mfma16(pa, vb, oacc[ni2]);
            }
        }
        __syncthreads();
    }
#pragma unroll
    for (int ni2 = 0; ni2 < 8; ++ni2) {
        int col = h * 128 + ni2 * 16 + l15;
#pragma unroll
        for (int r = 0; r < 4; ++r) {
            int row = qb * 64 + wave * 16 + 4 * l4 + r;
            attn[(size_t)row * 2048 + col] = f2b(oacc[ni2][r] / l_r[r]);
        }
    }
}

extern "C" void kernel_launch(void* const* d_in, const int* in_sizes, int n_in,
                              void* d_out, int out_size, void* d_ws, size_t ws_size,
                              hipStream_t stream) {
    (void)in_sizes; (void)n_in; (void)out_size; (void)ws_size;
    const float* x    = (const float*)d_in[0];
    const float* fcos = (const float*)d_in[2];
    const float* fsin = (const float*)d_in[3];
    const float* wqd  = (const float*)d_in[5];
    const float* bqd  = (const float*)d_in[6];
    const float* qnw  = (const float*)d_in[7];
    const float* wqu  = (const float*)d_in[8];
    const float* bqu  = (const float*)d_in[9];
    const float* wkvd = (const float*)d_in[10];
    const float* bkvd = (const float*)d_in[11];
    const float* kvnw = (const float*)d_in[12];
    const float* wkvu = (const float*)d_in[13];
    const float* bkvu = (const float*)d_in[14];
    const float* wo   = (const float*)d_in[15];
    const float* bwo  = (const float*)d_in[16];
    float* out = (float*)d_out;

    char* ws = (char*)d_ws;
    size_t off = 0;
    auto alloc = [&](size_t bytes) {
        void* p = ws + off;
        off += (bytes + 255) & ~(size_t)255;
        return p;
    };
    unsigned short* xb     = (unsigned short*)alloc(2048ull * 2048 * 2);
    unsigned short* wqd16  = (unsigned short*)alloc(1536ull * 2048 * 2);
    unsigned short* wqu16  = (unsigned short*)alloc(3072ull * 1536 * 2);
    unsigned short* wkvd16 = (unsigned short*)alloc(640ull * 2048 * 2);
    unsigned short* wkvu16 = (unsigned short*)alloc(4096ull * 512 * 2);
    char* slotA            = (char*)alloc(2048ull * 3072 * 4);  // qdown f32 | qup f32 | attn bf16
    unsigned short* qn16   = (unsigned short*)alloc(2048ull * 1536 * 2);
    unsigned short* qf16   = (unsigned short*)alloc(16ull * 2048 * 192 * 2);
    float* kvd32           = (float*)alloc(2048ull * 640 * 4);
    unsigned short* kvn16  = (unsigned short*)alloc(2048ull * 512 * 2);
    char* slotB            = (char*)alloc(2048ull * 4096 * 4);  // kvup f32 | wo bf16
    unsigned short* kf16   = (unsigned short*)alloc(16ull * 2048 * 192 * 2);
    unsigned short* vT16   = (unsigned short*)alloc(16ull * 128 * 2048 * 2);

    float* qdown32 = (float*)slotA;
    float* qup32   = (float*)slotA;
    unsigned short* attn16 = (unsigned short*)slotA;
    float* kvup32  = (float*)slotB;
    unsigned short* wo16 = (unsigned short*)slotB;

    // weight / activation converts
    cvt_f2b<<<4096, 256, 0, stream>>>(x, xb, 2048 * 2048 / 4);
    cvt_f2b<<<3072, 256, 0, stream>>>(wqd, wqd16, 1536 * 2048 / 4);
    cvt_f2b<<<4608, 256, 0, stream>>>(wqu, wqu16, 3072 * 1536 / 4);
    cvt_f2b_pad<<<1280, 256, 0, stream>>>(wkvd, wkvd16, 576, 2048, 640);
    cvt_f2b<<<2048, 256, 0, stream>>>(wkvu, wkvu16, 4096 * 512 / 4);

    // q path
    gemm_bt<<<16 * 12, 256, 0, stream>>>(xb, wqd16, bqd, qdown32, 2048, 1536, 2048, 1536, 16);
    rmsnorm_k<<<2048, 256, 0, stream>>>(qdown32, qnw, qn16, 1536, 1536);
    gemm_bt<<<16 * 24, 256, 0, stream>>>(qn16, wqu16, bqu, qup32, 2048, 3072, 1536, 3072, 16);

    // kv path
    gemm_bt<<<16 * 5, 256, 0, stream>>>(xb, wkvd16, bkvd, kvd32, 2048, 576, 2048, 640, 16);
    rmsnorm_k<<<2048, 256, 0, stream>>>(kvd32, kvnw, kvn16, 512, 640);
    gemm_bt<<<16 * 32, 256, 0, stream>>>(kvn16, wkvu16, bkvu, kvup32, 2048, 4096, 512, 4096, 16);

    // assemble attention operands
    assemble_q<<<2048, 256, 0, stream>>>(qup32, fcos, fsin, qf16);
    assemble_k<<<2048, 256, 0, stream>>>(kvup32, kvd32, fcos, fsin, kf16);
    assemble_v<<<dim3(32, 16), 256, 0, stream>>>(kvup32, vT16);

    // wo weights into slotB (kvup dead after assembles)
    cvt_f2b<<<4096, 256, 0, stream>>>(wo, wo16, 2048 * 2048 / 4);

    // attention + output projection
    flash_attn<<<512, 256, 0, stream>>>(qf16, kf16, vT16, attn16);
    gemm_bt<<<16 * 16, 256, 0, stream>>>(attn16, wo16, bwo, out, 2048, 2048, 2048, 2048, 16);
}

// Round 8
// 460.557 us; speedup vs baseline: 1.2668x; 1.0635x over previous
//
#include <hip/hip_runtime.h>
#include <math.h>

typedef __attribute__((ext_vector_type(8))) __bf16 bf16x8;
typedef __attribute__((ext_vector_type(8))) short short8;
typedef __attribute__((ext_vector_type(4))) float f32x4;
typedef __attribute__((ext_vector_type(4))) unsigned short u16x4;

#define S_LEN 2048
#define NHEAD 16

__device__ __forceinline__ unsigned short f2b(float f) {
    unsigned int u = __float_as_uint(f);
    u = (u + 0x7fffu + ((u >> 16) & 1u)) >> 16;
    return (unsigned short)u;
}

__device__ __forceinline__ f32x4 mfma16(short8 a, short8 b, f32x4 c) {
    return __builtin_amdgcn_mfma_f32_16x16x32_bf16(
        __builtin_bit_cast(bf16x8, a), __builtin_bit_cast(bf16x8, b), c, 0, 0, 0);
}

#define GLDS(gptr, lptr)                                                              \
    __builtin_amdgcn_global_load_lds(                                                 \
        (const __attribute__((address_space(1))) unsigned int*)(gptr),                \
        (__attribute__((address_space(3))) unsigned int*)(lptr), 16, 0, 0)

// ---------------- fp32 -> bf16 converts ----------------
__global__ __launch_bounds__(256) void cvt_f2b(const float* __restrict__ in,
                                               unsigned short* __restrict__ out, int n4) {
    int i = blockIdx.x * 256 + threadIdx.x;
    if (i >= n4) return;
    float4 v = ((const float4*)in)[i];
    u16x4 o;
    o[0] = f2b(v.x); o[1] = f2b(v.y); o[2] = f2b(v.z); o[3] = f2b(v.w);
    ((u16x4*)out)[i] = o;
}

__global__ __launch_bounds__(256) void cvt_f2b_pad(const float* __restrict__ in,
                                                   unsigned short* __restrict__ out,
                                                   int N, int K, int Npad) {
    int i = blockIdx.x * 256 + threadIdx.x;
    int total4 = Npad * (K >> 2);
    if (i >= total4) return;
    int r = (i * 4) / K;
    u16x4 o = {0, 0, 0, 0};
    if (r < N) {
        float4 v = ((const float4*)in)[i];
        o[0] = f2b(v.x); o[1] = f2b(v.y); o[2] = f2b(v.z); o[3] = f2b(v.w);
    }
    ((u16x4*)out)[i] = o;
}

// ---------------- GEMM: C[M x Npad](f32) = A[M x K](bf16) @ W[Npad x K]^T + bias ----
// 128x128 tile, BK=64, 2-phase double-buffered global_load_lds (T3-minimum):
// STAGE(t+1) issued BEFORE compute(t); single __syncthreads per K-step, so its
// vmcnt(0) drain lands after a full compute phase of latency cover. Grids here
// are ~1 block/CU (M=2048), so intra-block overlap is the only latency hiding.
__global__ __launch_bounds__(256) void gemm_bt(const unsigned short* __restrict__ A,
                                               const unsigned short* __restrict__ W,
                                               const float* __restrict__ bias,
                                               float* __restrict__ C,
                                               int M, int N, int K, int Npad,
                                               int tiles_m) {
    __shared__ __align__(16) unsigned short sA[2][128 * 64];
    __shared__ __align__(16) unsigned short sB[2][128 * 64];
    const int tid = threadIdx.x;
    const int wave = tid >> 6, lane = tid & 63;
    const int l15 = lane & 15, l4 = lane >> 4;
    const int wm = wave >> 1, wn = wave & 1;

    const int nwg = gridDim.x;
    const int q8 = nwg >> 3, r8 = nwg & 7;
    const int xcd = blockIdx.x & 7, ii = blockIdx.x >> 3;
    const int sw = ((xcd < r8) ? xcd * (q8 + 1) : r8 * (q8 + 1) + (xcd - r8) * q8) + ii;
    const int bm = sw % tiles_m, bn = sw / tiles_m;

    const unsigned short* Abase = A + (size_t)bm * 128 * K;
    const unsigned short* Wbase = W + (size_t)bn * 128 * K;
    // staging chunk c = j*256 + tid -> row r = c>>3, col-chunk c8 = c&7
    int srcoff[4];
#pragma unroll
    for (int j = 0; j < 4; ++j) {
        int c = j * 256 + tid;
        srcoff[j] = (c >> 3) * K + (c & 7) * 8;
    }

    auto STAGE = [&](int kt, int buf) {
#pragma unroll
        for (int j = 0; j < 4; ++j) {
            GLDS(Abase + kt * 64 + srcoff[j], (char*)sA[buf] + (j * 256 + wave * 64) * 16);
            GLDS(Wbase + kt * 64 + srcoff[j], (char*)sB[buf] + (j * 256 + wave * 64) * 16);
        }
    };

    f32x4 acc[4][4] = {};
    const int nkt = K >> 6;
    STAGE(0, 0);
    __syncthreads();
    for (int kt = 0; kt < nkt; ++kt) {
        const int cur = kt & 1;
        if (kt + 1 < nkt) STAGE(kt + 1, cur ^ 1);
        const unsigned short* pA = sA[cur];
        const unsigned short* pB = sB[cur];
#pragma unroll
        for (int ks = 0; ks < 2; ++ks) {
            short8 af[4], bf[4];
#pragma unroll
            for (int mi = 0; mi < 4; ++mi)
                af[mi] = *(const short8*)&pA[(wm * 64 + mi * 16 + l15) * 64 + ks * 32 + 8 * l4];
#pragma unroll
            for (int ni = 0; ni < 4; ++ni)
                bf[ni] = *(const short8*)&pB[(wn * 64 + ni * 16 + l15) * 64 + ks * 32 + 8 * l4];
#pragma unroll
            for (int mi = 0; mi < 4; ++mi)
#pragma unroll
                for (int ni = 0; ni < 4; ++ni)
                    acc[mi][ni] = mfma16(af[mi], bf[ni], acc[mi][ni]);
        }
        __syncthreads();
    }
#pragma unroll
    for (int mi = 0; mi < 4; ++mi) {
        int row = bm * 128 + wm * 64 + mi * 16 + 4 * l4;
#pragma unroll
        for (int ni = 0; ni < 4; ++ni) {
            int col = bn * 128 + wn * 64 + ni * 16 + l15;
            float b = (col < N) ? bias[col] : 0.f;
#pragma unroll
            for (int r = 0; r < 4; ++r)
                C[(size_t)(row + r) * Npad + col] = acc[mi][ni][r] + b;
        }
    }
}

// ---------------- RMS norm ----------------
__global__ __launch_bounds__(256) void rmsnorm_k(const float* __restrict__ in,
                                                 const float* __restrict__ w,
                                                 unsigned short* __restrict__ out,
                                                 int K, int ldin) {
    int row = blockIdx.x, tid = threadIdx.x;
    const float* p = in + (size_t)row * ldin;
    float ss = 0.f;
    for (int i = tid; i < K; i += 256) { float v = p[i]; ss += v * v; }
#pragma unroll
    for (int off = 1; off < 64; off <<= 1) ss += __shfl_xor(ss, off, 64);
    __shared__ float red[4];
    if ((tid & 63) == 0) red[tid >> 6] = ss;
    __syncthreads();
    float tot = red[0] + red[1] + red[2] + red[3];
    float rinv = rsqrtf(tot / (float)K + 1e-6f);
    for (int i = tid; i < K; i += 256)
        out[(size_t)row * K + i] = f2b(p[i] * rinv * w[i]);
}

// ---------------- assemble q ----------------
__global__ __launch_bounds__(256) void assemble_q(const float* __restrict__ qup,
                                                  const float* __restrict__ fcos,
                                                  const float* __restrict__ fsin,
                                                  unsigned short* __restrict__ qf) {
    int s = blockIdx.x, tid = threadIdx.x;
    const float scale = 0.07216878365f;  // 192^-0.5
    for (int idx = tid; idx < NHEAD * 128; idx += 256) {
        int h = idx >> 7, j = idx & 127;
        qf[((size_t)h * S_LEN + s) * 192 + j] = f2b(qup[(size_t)s * 3072 + h * 192 + j] * scale);
    }
    for (int idx = tid; idx < NHEAD * 32; idx += 256) {
        int h = idx >> 5, j = idx & 31;
        float x0 = qup[(size_t)s * 3072 + h * 192 + 128 + 2 * j];
        float x1 = qup[(size_t)s * 3072 + h * 192 + 128 + 2 * j + 1];
        float c = fcos[s * 32 + j], sn = fsin[s * 32 + j];
        size_t base = ((size_t)h * S_LEN + s) * 192 + 128 + 2 * j;
        qf[base]     = f2b((x0 * c - x1 * sn) * scale);
        qf[base + 1] = f2b((x0 * sn + x1 * c) * scale);
    }
}

// ---------------- assemble k ----------------
__global__ __launch_bounds__(256) void assemble_k(const float* __restrict__ kvup,
                                                  const float* __restrict__ kvd,
                                                  const float* __restrict__ fcos,
                                                  const float* __restrict__ fsin,
                                                  unsigned short* __restrict__ kf) {
    int s = blockIdx.x, tid = threadIdx.x;
    __shared__ unsigned short pe[64];
    if (tid < 32) {
        int j = tid;
        float x0 = kvd[(size_t)s * 640 + 512 + 2 * j];
        float x1 = kvd[(size_t)s * 640 + 512 + 2 * j + 1];
        float c = fcos[s * 32 + j], sn = fsin[s * 32 + j];
        pe[2 * j]     = f2b(x0 * c - x1 * sn);
        pe[2 * j + 1] = f2b(x0 * sn + x1 * c);
    }
    __syncthreads();
    for (int idx = tid; idx < NHEAD * 128; idx += 256) {
        int h = idx >> 7, j = idx & 127;
        kf[((size_t)h * S_LEN + s) * 192 + j] = f2b(kvup[(size_t)s * 4096 + h * 256 + j]);
    }
    for (int idx = tid; idx < NHEAD * 64; idx += 256) {
        int h = idx >> 6, j = idx & 63;
        kf[((size_t)h * S_LEN + s) * 192 + 128 + j] = pe[j];
    }
}

// ---------------- assemble v: tiled transpose, coalesced short8 stores ----------
__global__ __launch_bounds__(256) void assemble_v(const float* __restrict__ kvup,
                                                  unsigned short* __restrict__ vT) {
    __shared__ unsigned short t[64][136];
    int sb = blockIdx.x, h = blockIdx.y, tid = threadIdx.x;
#pragma unroll
    for (int i = 0; i < 8; ++i) {
        int idx = tid + i * 256;
        int s = idx >> 5, c4 = idx & 31;
        float4 v = *(const float4*)&kvup[(size_t)(sb * 64 + s) * 4096 + h * 256 + 128 + c4 * 4];
        t[s][c4 * 4 + 0] = f2b(v.x); t[s][c4 * 4 + 1] = f2b(v.y);
        t[s][c4 * 4 + 2] = f2b(v.z); t[s][c4 * 4 + 3] = f2b(v.w);
    }
    __syncthreads();
#pragma unroll
    for (int i = 0; i < 4; ++i) {
        int idx = tid + i * 256;
        int d = idx >> 3, s8 = idx & 7;
        short8 o;
#pragma unroll
        for (int j = 0; j < 8; ++j) o[j] = t[s8 * 8 + j][d];
        *(short8*)&vT[((size_t)h * 128 + d) * S_LEN + sb * 64 + s8 * 8] = o;
    }
}

// ---------------- flash attention, causal ----------------
// grid 512 flat, balanced qb pairing; XOR-swizzled LDS via pre-swizzled GLDS
// source (zero bank conflicts, no reg round-trip). 2-phase double-buffered
// K/V tiles — STAGE(kb+1) issued before compute(kb), one __syncthreads per tile
// so the vmcnt(0) drain sits after the QK^T+softmax+PV phase. LDS 88 KB.
__global__ __launch_bounds__(256) void flash_attn(const unsigned short* __restrict__ qf,
                                                  const unsigned short* __restrict__ kf,
                                                  const unsigned short* __restrict__ vT,
                                                  unsigned short* __restrict__ attn) {
    __shared__ __align__(16) unsigned short sK[2][64 * 192];    // swizzled [64][192]
    __shared__ __align__(16) unsigned short sV[2][128 * 64];    // swizzled [128][64]
    __shared__ __align__(16) unsigned short sP[4 * 16 * 64];    // swizzled [4][16][64]
    const int tid = threadIdx.x;
    const int wave = tid >> 6, lane = tid & 63;
    const int l15 = lane & 15, l4 = lane >> 4;
    const int bid = blockIdx.x;
    const int h = bid & 15, iph = bid >> 4;
    const int qb = (iph < 16) ? iph : 47 - iph;

    const unsigned short* kbase = kf + (size_t)h * S_LEN * 192;
    const unsigned short* vbase = vT + (size_t)h * 128 * S_LEN;

    // per-lane pre-swizzled source offsets (loop-invariant): LDS linear chunk
    // c = i*256+tid receives logical chunk (r, c8 ^ (r&7)).
    int ksrc[6];
#pragma unroll
    for (int i = 0; i < 6; ++i) {
        int c = i * 256 + tid, r = c / 24, c8 = c % 24;
        ksrc[i] = r * 192 + (c8 ^ (r & 7)) * 8;
    }
    int vsrc[4];
#pragma unroll
    for (int i = 0; i < 4; ++i) {
        int c = i * 256 + tid, d = c >> 3, k8 = c & 7;
        vsrc[i] = d * S_LEN + (k8 ^ (d & 7)) * 8;
    }

    auto STAGE = [&](int kb, int buf) {
        const unsigned short* kt = kbase + (size_t)kb * 64 * 192;
        const unsigned short* vt = vbase + (size_t)kb * 64;
#pragma unroll
        for (int i = 0; i < 6; ++i)
            GLDS(kt + ksrc[i], (char*)sK[buf] + (i * 256 + wave * 64) * 16);
#pragma unroll
        for (int i = 0; i < 4; ++i)
            GLDS(vt + vsrc[i], (char*)sV[buf] + (i * 256 + wave * 64) * 16);
    };

    short8 qfrag[6];
    {
        const unsigned short* qp =
            qf + ((size_t)h * S_LEN + qb * 64 + wave * 16 + l15) * 192 + 8 * l4;
#pragma unroll
        for (int ks = 0; ks < 6; ++ks) qfrag[ks] = *(const short8*)(qp + ks * 32);
    }
    f32x4 oacc[8] = {};
    float m_r[4] = {-INFINITY, -INFINITY, -INFINITY, -INFINITY};
    float l_r[4] = {0.f, 0.f, 0.f, 0.f};

    STAGE(0, 0);
    __syncthreads();
    for (int kb = 0; kb <= qb; ++kb) {
        const int cur = kb & 1;
        if (kb < qb) STAGE(kb + 1, cur ^ 1);
        const char* pK = (const char*)sK[cur];
        const char* pV = (const char*)sV[cur];

        f32x4 sc[4] = {};
#pragma unroll
        for (int ks = 0; ks < 6; ++ks)
#pragma unroll
            for (int ni = 0; ni < 4; ++ni) {
                int r = ni * 16 + l15;
                short8 bfr = *(const short8*)(pK + r * 384 + (((ks * 4 + l4) ^ (r & 7)) * 16));
                sc[ni] = mfma16(qfrag[ks], bfr, sc[ni]);
            }

        const bool diag = (kb == qb);
        float p[4][4], alpha[4];
#pragma unroll
        for (int r = 0; r < 4; ++r) {
            int qrow = wave * 16 + 4 * l4 + r;
            float mx = -1e30f;
#pragma unroll
            for (int ni = 0; ni < 4; ++ni) {
                float sv = sc[ni][r];
                if (diag && (ni * 16 + l15 > qrow)) sv = -1e30f;
                p[ni][r] = sv;
                mx = fmaxf(mx, sv);
            }
#pragma unroll
            for (int off = 1; off < 16; off <<= 1) mx = fmaxf(mx, __shfl_xor(mx, off, 16));
            float mnew = fmaxf(m_r[r], mx);
            alpha[r] = __expf(m_r[r] - mnew);
            float rs = 0.f;
#pragma unroll
            for (int ni = 0; ni < 4; ++ni) {
                float pe = __expf(p[ni][r] - mnew);
                p[ni][r] = pe;
                rs += pe;
            }
#pragma unroll
            for (int off = 1; off < 16; off <<= 1) rs += __shfl_xor(rs, off, 16);
            l_r[r] = l_r[r] * alpha[r] + rs;
            m_r[r] = mnew;
        }
#pragma unroll
        for (int ni2 = 0; ni2 < 8; ++ni2)
#pragma unroll
            for (int r = 0; r < 4; ++r) oacc[ni2][r] *= alpha[r];
#pragma unroll
        for (int ni = 0; ni < 4; ++ni)
#pragma unroll
            for (int r = 0; r < 4; ++r) {
                int prow = 4 * l4 + r;
                int pbyte = wave * 2048 + ((prow * 128 + (ni * 16 + l15) * 2) ^ ((prow & 7) << 4));
                *(unsigned short*)((char*)sP + pbyte) = f2b(p[ni][r]);
            }
#pragma unroll
        for (int ks2 = 0; ks2 < 2; ++ks2) {
            short8 pa = *(const short8*)((char*)sP + wave * 2048 + l15 * 128 +
                                         (((ks2 * 4 + l4) ^ (l15 & 7)) * 16));
#pragma unroll
            for (int ni2 = 0; ni2 < 8; ++ni2) {
                int d = ni2 * 16 + l15;
                short8 vb = *(const short8*)(pV + d * 128 + (((ks2 * 4 + l4) ^ (d & 7)) * 16));
                oacc[ni2] = mfma16(pa, vb, oacc[ni2]);
            }
        }
        __syncthreads();
    }
#pragma unroll
    for (int ni2 = 0; ni2 < 8; ++ni2) {
        int col = h * 128 + ni2 * 16 + l15;
#pragma unroll
        for (int r = 0; r < 4; ++r) {
            int row = qb * 64 + wave * 16 + 4 * l4 + r;
            attn[(size_t)row * 2048 + col] = f2b(oacc[ni2][r] / l_r[r]);
        }
    }
}

extern "C" void kernel_launch(void* const* d_in, const int* in_sizes, int n_in,
                              void* d_out, int out_size, void* d_ws, size_t ws_size,
                              hipStream_t stream) {
    (void)in_sizes; (void)n_in; (void)out_size; (void)ws_size;
    const float* x    = (const float*)d_in[0];
    const float* fcos = (const float*)d_in[2];
    const float* fsin = (const float*)d_in[3];
    const float* wqd  = (const float*)d_in[5];
    const float* bqd  = (const float*)d_in[6];
    const float* qnw  = (const float*)d_in[7];
    const float* wqu  = (const float*)d_in[8];
    const float* bqu  = (const float*)d_in[9];
    const float* wkvd = (const float*)d_in[10];
    const float* bkvd = (const float*)d_in[11];
    const float* kvnw = (const float*)d_in[12];
    const float* wkvu = (const float*)d_in[13];
    const float* bkvu = (const float*)d_in[14];
    const float* wo   = (const float*)d_in[15];
    const float* bwo  = (const float*)d_in[16];
    float* out = (float*)d_out;

    char* ws = (char*)d_ws;
    size_t off = 0;
    auto alloc = [&](size_t bytes) {
        void* p = ws + off;
        off += (bytes + 255) & ~(size_t)255;
        return p;
    };
    unsigned short* xb     = (unsigned short*)alloc(2048ull * 2048 * 2);
    unsigned short* wqd16  = (unsigned short*)alloc(1536ull * 2048 * 2);
    unsigned short* wqu16  = (unsigned short*)alloc(3072ull * 1536 * 2);
    unsigned short* wkvd16 = (unsigned short*)alloc(640ull * 2048 * 2);
    unsigned short* wkvu16 = (unsigned short*)alloc(4096ull * 512 * 2);
    char* slotA            = (char*)alloc(2048ull * 3072 * 4);  // qdown f32 | qup f32 | attn bf16
    unsigned short* qn16   = (unsigned short*)alloc(2048ull * 1536 * 2);
    unsigned short* qf16   = (unsigned short*)alloc(16ull * 2048 * 192 * 2);
    float* kvd32           = (float*)alloc(2048ull * 640 * 4);
    unsigned short* kvn16  = (unsigned short*)alloc(2048ull * 512 * 2);
    char* slotB            = (char*)alloc(2048ull * 4096 * 4);  // kvup f32 | wo bf16
    unsigned short* kf16   = (unsigned short*)alloc(16ull * 2048 * 192 * 2);
    unsigned short* vT16   = (unsigned short*)alloc(16ull * 128 * 2048 * 2);

    float* qdown32 = (float*)slotA;
    float* qup32   = (float*)slotA;
    unsigned short* attn16 = (unsigned short*)slotA;
    float* kvup32  = (float*)slotB;
    unsigned short* wo16 = (unsigned short*)slotB;

    // weight / activation converts
    cvt_f2b<<<4096, 256, 0, stream>>>(x, xb, 2048 * 2048 / 4);
    cvt_f2b<<<3072, 256, 0, stream>>>(wqd, wqd16, 1536 * 2048 / 4);
    cvt_f2b<<<4608, 256, 0, stream>>>(wqu, wqu16, 3072 * 1536 / 4);
    cvt_f2b_pad<<<1280, 256, 0, stream>>>(wkvd, wkvd16, 576, 2048, 640);
    cvt_f2b<<<2048, 256, 0, stream>>>(wkvu, wkvu16, 4096 * 512 / 4);

    // q path
    gemm_bt<<<16 * 12, 256, 0, stream>>>(xb, wqd16, bqd, qdown32, 2048, 1536, 2048, 1536, 16);
    rmsnorm_k<<<2048, 256, 0, stream>>>(qdown32, qnw, qn16, 1536, 1536);
    gemm_bt<<<16 * 24, 256, 0, stream>>>(qn16, wqu16, bqu, qup32, 2048, 3072, 1536, 3072, 16);

    // kv path
    gemm_bt<<<16 * 5, 256, 0, stream>>>(xb, wkvd16, bkvd, kvd32, 2048, 576, 2048, 640, 16);
    rmsnorm_k<<<2048, 256, 0, stream>>>(kvd32, kvnw, kvn16, 512, 640);
    gemm_bt<<<16 * 32, 256, 0, stream>>>(kvn16, wkvu16, bkvu, kvup32, 2048, 4096, 512, 4096, 16);

    // assemble attention operands
    assemble_q<<<2048, 256, 0, stream>>>(qup32, fcos, fsin, qf16);
    assemble_k<<<2048, 256, 0, stream>>>(kvup32, kvd32, fcos, fsin, kf16);
    assemble_v<<<dim3(32, 16), 256, 0, stream>>>(kvup32, vT16);

    // wo weights into slotB (kvup dead after assembles)
    cvt_f2b<<<4096, 256, 0, stream>>>(wo, wo16, 2048 * 2048 / 4);

    // attention + output projection
    flash_attn<<<512, 256, 0, stream>>>(qf16, kf16, vT16, attn16);
    gemm_bt<<<16 * 16, 256, 0, stream>>>(attn16, wo16, bwo, out, 2048, 2048, 2048, 2048, 16);
}